// Round 5
// baseline (116.491 us; speedup 1.0000x reference)
//
#include <hip/hip_runtime.h>

// CRF loss: mean_b( log Z_b - score_b ),  B=128, S=512, T=64 (mask all-ones).
//
// Parallel associative scan: alpha_511 = alpha_0 * PROD_i (E * diag(eem_i)).
// Phase 1 (crf_chunk_kernel<CH>): CH chunks x 128 batches waves; each wave
//   computes its chunk's 64x64 transfer matrix via the verified MFMA
//   recurrence on 64 identity basis columns. CH=32 -> 4096 waves = 4/SIMD
//   (VGPR-96 occupancy cap), vs R3's grid-limited 2/SIMD.
// Phase 2 (crf_combine_kernel<CH>): one wave per batch: path score (fused) +
//   chain alpha through the CH stored bf16 matrices (4-way ILP FMA chains),
//   logsumexp with end_t.

#define BB 128
#define SS 512
#define TT 64

typedef float f32x4 __attribute__((ext_vector_type(4)));
typedef short s16x8 __attribute__((ext_vector_type(8)));
typedef unsigned int u32x4 __attribute__((ext_vector_type(4)));

#define MFMA16(a, b, c) __builtin_amdgcn_mfma_f32_16x16x32_bf16((a), (b), (c), 0, 0, 0)

#define LOG2E 1.4426950408889634f
#define LN2   0.6931471805599453f

__device__ __forceinline__ unsigned pack_bf16_trunc(float hi, float lo) {
    return __builtin_amdgcn_perm(__float_as_uint(hi), __float_as_uint(lo), 0x07060302u);
}
__device__ __forceinline__ unsigned short bf16_rne(float x) {
    unsigned u = __float_as_uint(x);
    u += 0x7FFFu + ((u >> 16) & 1u);
    return (unsigned short)(u >> 16);
}
__device__ __forceinline__ float rdlane(float v, int lane) {
    return __uint_as_float(__builtin_amdgcn_readlane(__float_as_uint(v), lane));
}

// ---------------- Phase 1 ----------------
template<int L>
__device__ __forceinline__ void chunk_body(
    const float* __restrict__ emb, const int sbase, const s16x8 A[4][2],
    unsigned short* __restrict__ Mout, int* __restrict__ eoff_out,
    const int g, const int m, const int l)
{
    constexpr int FB = (L - 1) / 8;      // full 8-step groups
    constexpr int TL = L - 8 * FB;       // tail steps (7 or 8)
    const f32x4 Z = {0.f, 0.f, 0.f, 0.f};
    union BU { s16x8 v; unsigned u[4]; };
    BU Blo[4], Bhi[4];
    #pragma unroll
    for (int nb = 0; nb < 4; ++nb) {
        const int K = 16 * nb + m;
        #pragma unroll
        for (int r = 0; r < 4; ++r) {
            int k0 = 8 * g + 2 * r;
            Blo[nb].u[r] = ((k0 == K) ? 0x3F80u : 0u) | ((k0 + 1 == K) ? 0x3F800000u : 0u);
            int k1 = 32 + 8 * g + 2 * r;
            Bhi[nb].u[r] = ((k1 == K) ? 0x3F80u : 0u) | ((k1 + 1 == K) ? 0x3F800000u : 0u);
        }
    }

    const float* embg = emb + 8 * g;
    f32x4 raw[4][4];
    #pragma unroll
    for (int i = 0; i < 4; ++i) {
        const float* p = embg + (size_t)(sbase + i) * TT;
        raw[i][0] = *(const f32x4*)(p);
        raw[i][1] = *(const f32x4*)(p + 4);
        raw[i][2] = *(const f32x4*)(p + 32);
        raw[i][3] = *(const f32x4*)(p + 36);
    }
    f32x4 dfin[4][4];
    int eoff = 0, epend = 0;

#define NBODY(NB, RESC) do {                                                      \
    f32x4 c0 = MFMA16(A[0][0], Blo[NB].v, Z);                                     \
    f32x4 c1 = MFMA16(A[1][0], Blo[NB].v, Z);                                     \
    f32x4 c2 = MFMA16(A[2][0], Blo[NB].v, Z);                                     \
    f32x4 c3 = MFMA16(A[3][0], Blo[NB].v, Z);                                     \
    c0 = MFMA16(A[0][1], Bhi[NB].v, c0);                                          \
    c1 = MFMA16(A[1][1], Bhi[NB].v, c1);                                          \
    c2 = MFMA16(A[2][1], Bhi[NB].v, c2);                                          \
    c3 = MFMA16(A[3][1], Bhi[NB].v, c3);                                          \
    c0 *= CUR0; c1 *= CUR1; c2 *= CUR2; c3 *= CUR3;                               \
    if (RESC) {                                                                   \
        mx = fmaxf(mx, fmaxf(fmaxf(fmaxf(c0[0], c0[1]), fmaxf(c0[2], c0[3])),     \
                             fmaxf(fmaxf(c1[0], c1[1]), fmaxf(c1[2], c1[3]))));   \
        mx = fmaxf(mx, fmaxf(fmaxf(fmaxf(c2[0], c2[1]), fmaxf(c2[2], c2[3])),     \
                             fmaxf(fmaxf(c3[0], c3[1]), fmaxf(c3[2], c3[3]))));   \
    }                                                                             \
    Blo[NB].u[0] = pack_bf16_trunc(c0[1], c0[0]);                                 \
    Blo[NB].u[1] = pack_bf16_trunc(c0[3], c0[2]);                                 \
    Blo[NB].u[2] = pack_bf16_trunc(c1[1], c1[0]);                                 \
    Blo[NB].u[3] = pack_bf16_trunc(c1[3], c1[2]);                                 \
    Bhi[NB].u[0] = pack_bf16_trunc(c2[1], c2[0]);                                 \
    Bhi[NB].u[1] = pack_bf16_trunc(c2[3], c2[2]);                                 \
    Bhi[NB].u[2] = pack_bf16_trunc(c3[1], c3[0]);                                 \
    Bhi[NB].u[3] = pack_bf16_trunc(c3[3], c3[2]);                                 \
} while (0)

#define CURBLK(SL)                                                                \
    f32x4 r0 = raw[SL][0], r1 = raw[SL][1], r2 = raw[SL][2], r3 = raw[SL][3];     \
    const float fne = -(float)epend; epend = 0;                                   \
    f32x4 CUR0, CUR1, CUR2, CUR3;                                                 \
    CUR0[0] = exp2f(fmaf(r0[0], LOG2E, fne));                                     \
    CUR0[1] = exp2f(fmaf(r0[1], LOG2E, fne));                                     \
    CUR0[2] = exp2f(fmaf(r0[2], LOG2E, fne));                                     \
    CUR0[3] = exp2f(fmaf(r0[3], LOG2E, fne));                                     \
    CUR1[0] = exp2f(fmaf(r1[0], LOG2E, fne));                                     \
    CUR1[1] = exp2f(fmaf(r1[1], LOG2E, fne));                                     \
    CUR1[2] = exp2f(fmaf(r1[2], LOG2E, fne));                                     \
    CUR1[3] = exp2f(fmaf(r1[3], LOG2E, fne));                                     \
    CUR2[0] = exp2f(fmaf(r2[0], LOG2E, fne));                                     \
    CUR2[1] = exp2f(fmaf(r2[1], LOG2E, fne));                                     \
    CUR2[2] = exp2f(fmaf(r2[2], LOG2E, fne));                                     \
    CUR2[3] = exp2f(fmaf(r2[3], LOG2E, fne));                                     \
    CUR3[0] = exp2f(fmaf(r3[0], LOG2E, fne));                                     \
    CUR3[1] = exp2f(fmaf(r3[1], LOG2E, fne));                                     \
    CUR3[2] = exp2f(fmaf(r3[2], LOG2E, fne));                                     \
    CUR3[3] = exp2f(fmaf(r3[3], LOG2E, fne));

#define DOSTEP(SL, RESC, PRE, SIDX) do {                                          \
    CURBLK(SL)                                                                    \
    if (PRE) {                                                                    \
        const float* p_ = embg + (size_t)(SIDX) * TT;                             \
        raw[SL][0] = *(const f32x4*)(p_);                                         \
        raw[SL][1] = *(const f32x4*)(p_ + 4);                                     \
        raw[SL][2] = *(const f32x4*)(p_ + 32);                                    \
        raw[SL][3] = *(const f32x4*)(p_ + 36);                                    \
    }                                                                             \
    float mx = 0.f;                                                               \
    NBODY(0, RESC); NBODY(1, RESC); NBODY(2, RESC); NBODY(3, RESC);               \
    if (RESC) {                                                                   \
        mx = fmaxf(mx, __shfl_xor(mx, 1, 64));                                    \
        mx = fmaxf(mx, __shfl_xor(mx, 2, 64));                                    \
        mx = fmaxf(mx, __shfl_xor(mx, 4, 64));                                    \
        mx = fmaxf(mx, __shfl_xor(mx, 8, 64));                                    \
        mx = fmaxf(mx, __shfl_xor(mx, 16, 64));                                   \
        mx = fmaxf(mx, __shfl_xor(mx, 32, 64));                                   \
        int e_ = (__float_as_int(mx) >> 23) - 127;                                \
        eoff += e_;                                                               \
        epend = e_;                                                               \
    }                                                                             \
} while (0)

#define DOSTEPL(SL) do {                                                          \
    CURBLK(SL)                                                                    \
    _Pragma("unroll")                                                             \
    for (int nb = 0; nb < 4; ++nb) {                                              \
        f32x4 c0 = MFMA16(A[0][0], Blo[nb].v, Z);                                 \
        f32x4 c1 = MFMA16(A[1][0], Blo[nb].v, Z);                                 \
        f32x4 c2 = MFMA16(A[2][0], Blo[nb].v, Z);                                 \
        f32x4 c3 = MFMA16(A[3][0], Blo[nb].v, Z);                                 \
        c0 = MFMA16(A[0][1], Bhi[nb].v, c0);                                      \
        c1 = MFMA16(A[1][1], Bhi[nb].v, c1);                                      \
        c2 = MFMA16(A[2][1], Bhi[nb].v, c2);                                      \
        c3 = MFMA16(A[3][1], Bhi[nb].v, c3);                                      \
        dfin[nb][0] = c0 * CUR0;                                                  \
        dfin[nb][1] = c1 * CUR1;                                                  \
        dfin[nb][2] = c2 * CUR2;                                                  \
        dfin[nb][3] = c3 * CUR3;                                                  \
    }                                                                             \
} while (0)

    #pragma unroll 1
    for (int ob = 0; ob < FB; ++ob) {
        const int sb4 = sbase + 8 * ob + 4;
        DOSTEP(0, 0, 1, sb4 + 0);
        DOSTEP(1, 0, 1, sb4 + 1);
        DOSTEP(2, 0, 1, sb4 + 2);
        DOSTEP(3, 0, 1, sb4 + 3);
        DOSTEP(0, 0, 1, sb4 + 4);
        DOSTEP(1, 0, 1, sb4 + 5);
        DOSTEP(2, 0, 1, sb4 + 6);
        DOSTEP(3, 1, 1, sb4 + 7);
    }
    {
        const int sb4 = sbase + 8 * FB + 4;
        if constexpr (TL == 8) {
            DOSTEP(0, 0, 1, sb4 + 0);
            DOSTEP(1, 0, 1, sb4 + 1);
            DOSTEP(2, 0, 1, sb4 + 2);
            DOSTEP(3, 0, 1, sb4 + 3);
            DOSTEP(0, 0, 0, 0);
            DOSTEP(1, 0, 0, 0);
            DOSTEP(2, 0, 0, 0);
            DOSTEPL(3);
        } else {  // TL == 7
            DOSTEP(0, 0, 1, sb4 + 0);
            DOSTEP(1, 0, 1, sb4 + 1);
            DOSTEP(2, 0, 1, sb4 + 2);
            DOSTEP(3, 0, 0, 0);
            DOSTEP(0, 0, 0, 0);
            DOSTEP(1, 0, 0, 0);
            DOSTEPL(2);
        }
    }
#undef DOSTEPL
#undef DOSTEP
#undef CURBLK
#undef NBODY

    // epilogue: exact-pow2 normalize, store M[k][j] bf16
    float mx = 0.f;
    #pragma unroll
    for (int nb = 0; nb < 4; ++nb)
        #pragma unroll
        for (int t = 0; t < 4; ++t) {
            f32x4 v = dfin[nb][t];
            mx = fmaxf(mx, fmaxf(fmaxf(v[0], v[1]), fmaxf(v[2], v[3])));
        }
    #pragma unroll
    for (int sh = 1; sh < 64; sh <<= 1) mx = fmaxf(mx, __shfl_xor(mx, sh, 64));
    int e = (__float_as_int(mx) >> 23) - 127;
    eoff += e;
    const float scl = __int_as_float((127 - e) << 23);
    #pragma unroll
    for (int nb = 0; nb < 4; ++nb) {
        f32x4 d0 = dfin[nb][0] * scl, d1 = dfin[nb][1] * scl;
        f32x4 d2 = dfin[nb][2] * scl, d3 = dfin[nb][3] * scl;
        const int row = (16 * nb + m) * TT;
        u32x4 w0, w1;
        w0[0] = pack_bf16_trunc(d0[1], d0[0]);
        w0[1] = pack_bf16_trunc(d0[3], d0[2]);
        w0[2] = pack_bf16_trunc(d1[1], d1[0]);
        w0[3] = pack_bf16_trunc(d1[3], d1[2]);
        w1[0] = pack_bf16_trunc(d2[1], d2[0]);
        w1[1] = pack_bf16_trunc(d2[3], d2[2]);
        w1[2] = pack_bf16_trunc(d3[1], d3[0]);
        w1[3] = pack_bf16_trunc(d3[3], d3[2]);
        *(u32x4*)(Mout + row + 8 * g)      = w0;
        *(u32x4*)(Mout + row + 32 + 8 * g) = w1;
    }
    if (l == 0) *eoff_out = eoff;
}

template<int CH>
__global__ __launch_bounds__(256, 4) void crf_chunk_kernel(
    const float* __restrict__ emissions, const float* __restrict__ transitions,
    unsigned short* __restrict__ M, int* __restrict__ eoffs)
{
    constexpr int SC = SS / CH;
    const int tid = threadIdx.x;
    const int l = tid & 63;
    const int w = tid >> 6;
    const int g = l >> 4;
    const int m = l & 15;
    const int b = blockIdx.x / (CH / 4);
    const int c = (blockIdx.x % (CH / 4)) * 4 + w;
    const float* emb = emissions + (size_t)b * SS * TT;

    // A fragments (verified): A[t][h] elem j = bf16(exp(trans[k][ps])),
    // k = 32h + 8g + j, ps = 8*(m>>2) + 4*(t&1) + (m&3) + 32*(t>>1)
    s16x8 A[4][2];
    #pragma unroll
    for (int t = 0; t < 4; ++t) {
        const int ps = 8 * (m >> 2) + 4 * (t & 1) + (m & 3) + 32 * (t >> 1);
        #pragma unroll
        for (int h = 0; h < 2; ++h) {
            union { s16x8 v; unsigned short s[8]; } u;
            #pragma unroll
            for (int j = 0; j < 8; ++j) {
                int k = 32 * h + 8 * g + j;
                u.s[j] = bf16_rne(exp2f(transitions[k * TT + ps] * LOG2E));
            }
            A[t][h] = u.v;
        }
    }

    unsigned short* Mout = M + (size_t)(b * CH + c) * (TT * TT);
    int* eo = eoffs + b * CH + c;
    const int sbase = SC * c + 1;
    if (c == CH - 1) chunk_body<SC - 1>(emb, sbase, A, Mout, eo, g, m, l);
    else             chunk_body<SC>(emb, sbase, A, Mout, eo, g, m, l);
}

// ---------------- Phase 2: score (fused) + chain + logsumexp ----------------
template<int CH>
__global__ __launch_bounds__(64) void crf_combine_kernel(
    const float* __restrict__ emissions, const float* __restrict__ transitions,
    const float* __restrict__ start_t, const float* __restrict__ end_t,
    const int* __restrict__ tags, const unsigned short* __restrict__ M,
    const int* __restrict__ eoffs, float* __restrict__ res)
{
    const int b = blockIdx.x;
    const int j = threadIdx.x;
    const float* em = emissions + (size_t)b * SS * TT;

    // path score
    float sc = 0.f;
    #pragma unroll
    for (int r = 0; r < SS / TT; ++r) {
        int i = j + r * TT;
        int cur = tags[b * SS + i];
        if (i > 0) {
            int prev = tags[b * SS + i - 1];
            sc += transitions[prev * TT + cur] + em[i * TT + cur];
        } else {
            sc += start_t[cur] + em[cur];
        }
    }
    if (j == 0) sc += end_t[tags[b * SS + SS - 1]];
    #pragma unroll
    for (int s = 1; s < 64; s <<= 1) sc += __shfl_xor(sc, s, 64);

    // chain alpha through CH chunk matrices (4-way ILP FMA chains)
    float a = exp2f((start_t[j] + em[j]) * LOG2E);
    int eoff = 0;
    #pragma unroll 1
    for (int c = 0; c < CH; ++c) {
        const unsigned short* Mc = M + (size_t)(b * CH + c) * (TT * TT) + j;
        float acc0 = 0.f, acc1 = 0.f, acc2 = 0.f, acc3 = 0.f;
        #pragma unroll
        for (int q = 0; q < 16; ++q) {
            float m0 = __uint_as_float(((unsigned)Mc[(q)      * TT]) << 16);
            float m1 = __uint_as_float(((unsigned)Mc[(16 + q) * TT]) << 16);
            float m2 = __uint_as_float(((unsigned)Mc[(32 + q) * TT]) << 16);
            float m3 = __uint_as_float(((unsigned)Mc[(48 + q) * TT]) << 16);
            acc0 = fmaf(rdlane(a, q),      m0, acc0);
            acc1 = fmaf(rdlane(a, 16 + q), m1, acc1);
            acc2 = fmaf(rdlane(a, 32 + q), m2, acc2);
            acc3 = fmaf(rdlane(a, 48 + q), m3, acc3);
        }
        float acc = (acc0 + acc1) + (acc2 + acc3);
        float mxv = acc;
        #pragma unroll
        for (int sh = 1; sh < 64; sh <<= 1) mxv = fmaxf(mxv, __shfl_xor(mxv, sh, 64));
        int e = (__float_as_int(mxv) >> 23) - 127;
        a = acc * __int_as_float((127 - e) << 23);
        eoff += e + eoffs[b * CH + c];
    }
    float v = a * exp2f(end_t[j] * LOG2E);
    #pragma unroll
    for (int sh = 1; sh < 64; sh <<= 1) v += __shfl_xor(v, sh, 64);
    if (j == 0) res[b] = (log2f(v) + (float)eoff) * LN2 - sc;
}

// ---------------- final mean ----------------
__global__ __launch_bounds__(64) void crf_reduce_kernel(
    const float* __restrict__ res, float* __restrict__ out)
{
    int l = threadIdx.x;
    float v = res[l] + res[l + 64];
    #pragma unroll
    for (int s = 1; s < 64; s <<= 1) v += __shfl_xor(v, s, 64);
    if (l == 0) out[0] = v * (1.0f / (float)BB);
}

extern "C" void kernel_launch(void* const* d_in, const int* in_sizes, int n_in,
                              void* d_out, int out_size, void* d_ws, size_t ws_size,
                              hipStream_t stream) {
    const float* emissions   = (const float*)d_in[0];
    const float* transitions = (const float*)d_in[1];
    const float* start_t     = (const float*)d_in[2];
    const float* end_t       = (const float*)d_in[3];
    const int*   tags        = (const int*)d_in[4];

    float* res   = (float*)d_ws;                              // 128 floats
    int*   eoffs = (int*)((char*)d_ws + 512);                 // <= 4096 ints
    unsigned short* M = (unsigned short*)((char*)d_ws + 65536);

    const size_t need32 = 65536 + (size_t)BB * 32 * TT * TT * 2;  // ~33.6 MB
    const size_t need16 = 65536 + (size_t)BB * 16 * TT * TT * 2;  // ~16.8 MB
    if (ws_size >= need32) {
        crf_chunk_kernel<32><<<BB * 8, 256, 0, stream>>>(emissions, transitions, M, eoffs);
        crf_combine_kernel<32><<<BB, 64, 0, stream>>>(emissions, transitions, start_t,
                                                      end_t, tags, M, eoffs, res);
    } else if (ws_size >= need16) {
        crf_chunk_kernel<16><<<BB * 4, 256, 0, stream>>>(emissions, transitions, M, eoffs);
        crf_combine_kernel<16><<<BB, 64, 0, stream>>>(emissions, transitions, start_t,
                                                      end_t, tags, M, eoffs, res);
    } else {
        crf_chunk_kernel<8><<<BB * 2, 256, 0, stream>>>(emissions, transitions, M, eoffs);
        crf_combine_kernel<8><<<BB, 64, 0, stream>>>(emissions, transitions, start_t,
                                                     end_t, tags, M, eoffs, res);
    }
    crf_reduce_kernel<<<1, 64, 0, stream>>>(res, (float*)d_out);
}

// Round 6
// 90.898 us; speedup vs baseline: 1.2816x; 1.2816x over previous
//
#include <hip/hip_runtime.h>

// CRF loss: mean_b( log Z_b - score_b ),  B=128, S=512, T=64 (mask all-ones).
//
// Parallel associative scan: alpha_511 = alpha_0 * PROD_i (E * diag(eem_i)).
// Phase 0 (crf_atab_kernel): precompute per-lane A-fragment table (16 KB).
// Phase 1 (crf_chunk_kernel<CH>): CH chunks x 128 batches waves; each wave
//   computes its chunk's 64x64 transfer matrix via the verified MFMA
//   recurrence on 64 identity basis columns. CH=32 -> 4096 waves = 4/SIMD.
//   launch_bounds(256,2) = R3's known-good codegen (96 VGPR, no spill);
//   R4's (256,4) forced 64 VGPR and spilled every step (WRITE_SIZE 114 MB).
// Phase 2 (crf_combine_kernel<CH>): one wave per batch: path score (fused) +
//   chain alpha through the CH stored bf16 matrices, logsumexp with end_t.

#define BB 128
#define SS 512
#define TT 64

typedef float f32x4 __attribute__((ext_vector_type(4)));
typedef short s16x8 __attribute__((ext_vector_type(8)));
typedef unsigned int u32x4 __attribute__((ext_vector_type(4)));

#define MFMA16(a, b, c) __builtin_amdgcn_mfma_f32_16x16x32_bf16((a), (b), (c), 0, 0, 0)

#define LOG2E 1.4426950408889634f
#define LN2   0.6931471805599453f

__device__ __forceinline__ unsigned pack_bf16_trunc(float hi, float lo) {
    return __builtin_amdgcn_perm(__float_as_uint(hi), __float_as_uint(lo), 0x07060302u);
}
__device__ __forceinline__ unsigned short bf16_rne(float x) {
    unsigned u = __float_as_uint(x);
    u += 0x7FFFu + ((u >> 16) & 1u);
    return (unsigned short)(u >> 16);
}
__device__ __forceinline__ float rdlane(float v, int lane) {
    return __uint_as_float(__builtin_amdgcn_readlane(__float_as_uint(v), lane));
}

// ---------------- Phase 0: A-fragment table ----------------
// atab[((t*2+h)*64 + l) * 8 + j] = bf16(exp(trans[(32h+8g+j)][ps(t,m)]))
// with g=l>>4, m=l&15, ps = 8*(m>>2) + 4*(t&1) + (m&3) + 32*(t>>1)
__global__ __launch_bounds__(64) void crf_atab_kernel(
    const float* __restrict__ transitions, unsigned short* __restrict__ atab)
{
    const int l = threadIdx.x;
    const int g = l >> 4;
    const int m = l & 15;
    #pragma unroll
    for (int t = 0; t < 4; ++t) {
        const int ps = 8 * (m >> 2) + 4 * (t & 1) + (m & 3) + 32 * (t >> 1);
        #pragma unroll
        for (int h = 0; h < 2; ++h) {
            #pragma unroll
            for (int j = 0; j < 8; ++j) {
                int k = 32 * h + 8 * g + j;
                atab[((t * 2 + h) * 64 + l) * 8 + j] =
                    bf16_rne(exp2f(transitions[k * TT + ps] * LOG2E));
            }
        }
    }
}

// ---------------- Phase 1 ----------------
template<int L>
__device__ __forceinline__ void chunk_body(
    const float* __restrict__ emb, const int sbase, const s16x8 A[4][2],
    unsigned short* __restrict__ Mout, int* __restrict__ eoff_out,
    const int g, const int m, const int l)
{
    constexpr int FB = (L - 1) / 8;      // full 8-step groups
    constexpr int TL = L - 8 * FB;       // tail steps (7 or 8)
    const f32x4 Z = {0.f, 0.f, 0.f, 0.f};
    union BU { s16x8 v; unsigned u[4]; };
    BU Blo[4], Bhi[4];
    #pragma unroll
    for (int nb = 0; nb < 4; ++nb) {
        const int K = 16 * nb + m;
        #pragma unroll
        for (int r = 0; r < 4; ++r) {
            int k0 = 8 * g + 2 * r;
            Blo[nb].u[r] = ((k0 == K) ? 0x3F80u : 0u) | ((k0 + 1 == K) ? 0x3F800000u : 0u);
            int k1 = 32 + 8 * g + 2 * r;
            Bhi[nb].u[r] = ((k1 == K) ? 0x3F80u : 0u) | ((k1 + 1 == K) ? 0x3F800000u : 0u);
        }
    }

    const float* embg = emb + 8 * g;
    f32x4 raw[4][4];
    #pragma unroll
    for (int i = 0; i < 4; ++i) {
        const float* p = embg + (size_t)(sbase + i) * TT;
        raw[i][0] = *(const f32x4*)(p);
        raw[i][1] = *(const f32x4*)(p + 4);
        raw[i][2] = *(const f32x4*)(p + 32);
        raw[i][3] = *(const f32x4*)(p + 36);
    }
    f32x4 dfin[4][4];
    int eoff = 0, epend = 0;

#define NBODY(NB, RESC) do {                                                      \
    f32x4 c0 = MFMA16(A[0][0], Blo[NB].v, Z);                                     \
    f32x4 c1 = MFMA16(A[1][0], Blo[NB].v, Z);                                     \
    f32x4 c2 = MFMA16(A[2][0], Blo[NB].v, Z);                                     \
    f32x4 c3 = MFMA16(A[3][0], Blo[NB].v, Z);                                     \
    c0 = MFMA16(A[0][1], Bhi[NB].v, c0);                                          \
    c1 = MFMA16(A[1][1], Bhi[NB].v, c1);                                          \
    c2 = MFMA16(A[2][1], Bhi[NB].v, c2);                                          \
    c3 = MFMA16(A[3][1], Bhi[NB].v, c3);                                          \
    c0 *= CUR0; c1 *= CUR1; c2 *= CUR2; c3 *= CUR3;                               \
    if (RESC) {                                                                   \
        mx = fmaxf(mx, fmaxf(fmaxf(fmaxf(c0[0], c0[1]), fmaxf(c0[2], c0[3])),     \
                             fmaxf(fmaxf(c1[0], c1[1]), fmaxf(c1[2], c1[3]))));   \
        mx = fmaxf(mx, fmaxf(fmaxf(fmaxf(c2[0], c2[1]), fmaxf(c2[2], c2[3])),     \
                             fmaxf(fmaxf(c3[0], c3[1]), fmaxf(c3[2], c3[3]))));   \
    }                                                                             \
    Blo[NB].u[0] = pack_bf16_trunc(c0[1], c0[0]);                                 \
    Blo[NB].u[1] = pack_bf16_trunc(c0[3], c0[2]);                                 \
    Blo[NB].u[2] = pack_bf16_trunc(c1[1], c1[0]);                                 \
    Blo[NB].u[3] = pack_bf16_trunc(c1[3], c1[2]);                                 \
    Bhi[NB].u[0] = pack_bf16_trunc(c2[1], c2[0]);                                 \
    Bhi[NB].u[1] = pack_bf16_trunc(c2[3], c2[2]);                                 \
    Bhi[NB].u[2] = pack_bf16_trunc(c3[1], c3[0]);                                 \
    Bhi[NB].u[3] = pack_bf16_trunc(c3[3], c3[2]);                                 \
} while (0)

#define CURBLK(SL)                                                                \
    f32x4 r0 = raw[SL][0], r1 = raw[SL][1], r2 = raw[SL][2], r3 = raw[SL][3];     \
    const float fne = -(float)epend; epend = 0;                                   \
    f32x4 CUR0, CUR1, CUR2, CUR3;                                                 \
    CUR0[0] = exp2f(fmaf(r0[0], LOG2E, fne));                                     \
    CUR0[1] = exp2f(fmaf(r0[1], LOG2E, fne));                                     \
    CUR0[2] = exp2f(fmaf(r0[2], LOG2E, fne));                                     \
    CUR0[3] = exp2f(fmaf(r0[3], LOG2E, fne));                                     \
    CUR1[0] = exp2f(fmaf(r1[0], LOG2E, fne));                                     \
    CUR1[1] = exp2f(fmaf(r1[1], LOG2E, fne));                                     \
    CUR1[2] = exp2f(fmaf(r1[2], LOG2E, fne));                                     \
    CUR1[3] = exp2f(fmaf(r1[3], LOG2E, fne));                                     \
    CUR2[0] = exp2f(fmaf(r2[0], LOG2E, fne));                                     \
    CUR2[1] = exp2f(fmaf(r2[1], LOG2E, fne));                                     \
    CUR2[2] = exp2f(fmaf(r2[2], LOG2E, fne));                                     \
    CUR2[3] = exp2f(fmaf(r2[3], LOG2E, fne));                                     \
    CUR3[0] = exp2f(fmaf(r3[0], LOG2E, fne));                                     \
    CUR3[1] = exp2f(fmaf(r3[1], LOG2E, fne));                                     \
    CUR3[2] = exp2f(fmaf(r3[2], LOG2E, fne));                                     \
    CUR3[3] = exp2f(fmaf(r3[3], LOG2E, fne));

#define DOSTEP(SL, RESC, PRE, SIDX) do {                                          \
    CURBLK(SL)                                                                    \
    if (PRE) {                                                                    \
        const float* p_ = embg + (size_t)(SIDX) * TT;                             \
        raw[SL][0] = *(const f32x4*)(p_);                                         \
        raw[SL][1] = *(const f32x4*)(p_ + 4);                                     \
        raw[SL][2] = *(const f32x4*)(p_ + 32);                                    \
        raw[SL][3] = *(const f32x4*)(p_ + 36);                                    \
    }                                                                             \
    float mx = 0.f;                                                               \
    NBODY(0, RESC); NBODY(1, RESC); NBODY(2, RESC); NBODY(3, RESC);               \
    if (RESC) {                                                                   \
        mx = fmaxf(mx, __shfl_xor(mx, 1, 64));                                    \
        mx = fmaxf(mx, __shfl_xor(mx, 2, 64));                                    \
        mx = fmaxf(mx, __shfl_xor(mx, 4, 64));                                    \
        mx = fmaxf(mx, __shfl_xor(mx, 8, 64));                                    \
        mx = fmaxf(mx, __shfl_xor(mx, 16, 64));                                   \
        mx = fmaxf(mx, __shfl_xor(mx, 32, 64));                                   \
        int e_ = (__float_as_int(mx) >> 23) - 127;                                \
        eoff += e_;                                                               \
        epend = e_;                                                               \
    }                                                                             \
} while (0)

#define DOSTEPL(SL) do {                                                          \
    CURBLK(SL)                                                                    \
    _Pragma("unroll")                                                             \
    for (int nb = 0; nb < 4; ++nb) {                                              \
        f32x4 c0 = MFMA16(A[0][0], Blo[nb].v, Z);                                 \
        f32x4 c1 = MFMA16(A[1][0], Blo[nb].v, Z);                                 \
        f32x4 c2 = MFMA16(A[2][0], Blo[nb].v, Z);                                 \
        f32x4 c3 = MFMA16(A[3][0], Blo[nb].v, Z);                                 \
        c0 = MFMA16(A[0][1], Bhi[nb].v, c0);                                      \
        c1 = MFMA16(A[1][1], Bhi[nb].v, c1);                                      \
        c2 = MFMA16(A[2][1], Bhi[nb].v, c2);                                      \
        c3 = MFMA16(A[3][1], Bhi[nb].v, c3);                                      \
        dfin[nb][0] = c0 * CUR0;                                                  \
        dfin[nb][1] = c1 * CUR1;                                                  \
        dfin[nb][2] = c2 * CUR2;                                                  \
        dfin[nb][3] = c3 * CUR3;                                                  \
    }                                                                             \
} while (0)

    #pragma unroll 1
    for (int ob = 0; ob < FB; ++ob) {
        const int sb4 = sbase + 8 * ob + 4;
        DOSTEP(0, 0, 1, sb4 + 0);
        DOSTEP(1, 0, 1, sb4 + 1);
        DOSTEP(2, 0, 1, sb4 + 2);
        DOSTEP(3, 0, 1, sb4 + 3);
        DOSTEP(0, 0, 1, sb4 + 4);
        DOSTEP(1, 0, 1, sb4 + 5);
        DOSTEP(2, 0, 1, sb4 + 6);
        DOSTEP(3, 1, 1, sb4 + 7);
    }
    {
        const int sb4 = sbase + 8 * FB + 4;
        if constexpr (TL == 8) {
            DOSTEP(0, 0, 1, sb4 + 0);
            DOSTEP(1, 0, 1, sb4 + 1);
            DOSTEP(2, 0, 1, sb4 + 2);
            DOSTEP(3, 0, 1, sb4 + 3);
            DOSTEP(0, 0, 0, 0);
            DOSTEP(1, 0, 0, 0);
            DOSTEP(2, 0, 0, 0);
            DOSTEPL(3);
        } else {  // TL == 7
            DOSTEP(0, 0, 1, sb4 + 0);
            DOSTEP(1, 0, 1, sb4 + 1);
            DOSTEP(2, 0, 1, sb4 + 2);
            DOSTEP(3, 0, 0, 0);
            DOSTEP(0, 0, 0, 0);
            DOSTEP(1, 0, 0, 0);
            DOSTEPL(2);
        }
    }
#undef DOSTEPL
#undef DOSTEP
#undef CURBLK
#undef NBODY

    // epilogue: exact-pow2 normalize, store M[k][j] bf16
    float mx = 0.f;
    #pragma unroll
    for (int nb = 0; nb < 4; ++nb)
        #pragma unroll
        for (int t = 0; t < 4; ++t) {
            f32x4 v = dfin[nb][t];
            mx = fmaxf(mx, fmaxf(fmaxf(v[0], v[1]), fmaxf(v[2], v[3])));
        }
    #pragma unroll
    for (int sh = 1; sh < 64; sh <<= 1) mx = fmaxf(mx, __shfl_xor(mx, sh, 64));
    int e = (__float_as_int(mx) >> 23) - 127;
    eoff += e;
    const float scl = __int_as_float((127 - e) << 23);
    #pragma unroll
    for (int nb = 0; nb < 4; ++nb) {
        f32x4 d0 = dfin[nb][0] * scl, d1 = dfin[nb][1] * scl;
        f32x4 d2 = dfin[nb][2] * scl, d3 = dfin[nb][3] * scl;
        const int row = (16 * nb + m) * TT;
        u32x4 w0, w1;
        w0[0] = pack_bf16_trunc(d0[1], d0[0]);
        w0[1] = pack_bf16_trunc(d0[3], d0[2]);
        w0[2] = pack_bf16_trunc(d1[1], d1[0]);
        w0[3] = pack_bf16_trunc(d1[3], d1[2]);
        w1[0] = pack_bf16_trunc(d2[1], d2[0]);
        w1[1] = pack_bf16_trunc(d2[3], d2[2]);
        w1[2] = pack_bf16_trunc(d3[1], d3[0]);
        w1[3] = pack_bf16_trunc(d3[3], d3[2]);
        *(u32x4*)(Mout + row + 8 * g)      = w0;
        *(u32x4*)(Mout + row + 32 + 8 * g) = w1;
    }
    if (l == 0) *eoff_out = eoff;
}

template<int CH>
__global__ __launch_bounds__(256, 2) void crf_chunk_kernel(
    const float* __restrict__ emissions, const unsigned short* __restrict__ atab,
    unsigned short* __restrict__ M, int* __restrict__ eoffs)
{
    constexpr int SC = SS / CH;
    const int tid = threadIdx.x;
    const int l = tid & 63;
    const int w = tid >> 6;
    const int g = l >> 4;
    const int m = l & 15;
    const int b = blockIdx.x / (CH / 4);
    const int c = (blockIdx.x % (CH / 4)) * 4 + w;
    const float* emb = emissions + (size_t)b * SS * TT;

    // A fragments from precomputed table: 8 coalesced 16B loads (L2-hot)
    s16x8 A[4][2];
    #pragma unroll
    for (int t = 0; t < 4; ++t)
        #pragma unroll
        for (int h = 0; h < 2; ++h)
            A[t][h] = *(const s16x8*)(atab + ((t * 2 + h) * 64 + l) * 8);

    unsigned short* Mout = M + (size_t)(b * CH + c) * (TT * TT);
    int* eo = eoffs + b * CH + c;
    const int sbase = SC * c + 1;
    if (c == CH - 1) chunk_body<SC - 1>(emb, sbase, A, Mout, eo, g, m, l);
    else             chunk_body<SC>(emb, sbase, A, Mout, eo, g, m, l);
}

// ---------------- Phase 2: score (fused) + chain + logsumexp ----------------
template<int CH>
__global__ __launch_bounds__(64) void crf_combine_kernel(
    const float* __restrict__ emissions, const float* __restrict__ transitions,
    const float* __restrict__ start_t, const float* __restrict__ end_t,
    const int* __restrict__ tags, const unsigned short* __restrict__ M,
    const int* __restrict__ eoffs, float* __restrict__ res)
{
    const int b = blockIdx.x;
    const int j = threadIdx.x;
    const float* em = emissions + (size_t)b * SS * TT;

    // path score
    float sc = 0.f;
    #pragma unroll
    for (int r = 0; r < SS / TT; ++r) {
        int i = j + r * TT;
        int cur = tags[b * SS + i];
        if (i > 0) {
            int prev = tags[b * SS + i - 1];
            sc += transitions[prev * TT + cur] + em[i * TT + cur];
        } else {
            sc += start_t[cur] + em[cur];
        }
    }
    if (j == 0) sc += end_t[tags[b * SS + SS - 1]];
    #pragma unroll
    for (int s = 1; s < 64; s <<= 1) sc += __shfl_xor(sc, s, 64);

    // chain alpha through CH chunk matrices (4-way ILP FMA chains)
    float a = exp2f((start_t[j] + em[j]) * LOG2E);
    int eoff = 0;
    #pragma unroll 1
    for (int c = 0; c < CH; ++c) {
        const unsigned short* Mc = M + (size_t)(b * CH + c) * (TT * TT) + j;
        float acc0 = 0.f, acc1 = 0.f, acc2 = 0.f, acc3 = 0.f;
        #pragma unroll
        for (int q = 0; q < 16; ++q) {
            float m0 = __uint_as_float(((unsigned)Mc[(q)      * TT]) << 16);
            float m1 = __uint_as_float(((unsigned)Mc[(16 + q) * TT]) << 16);
            float m2 = __uint_as_float(((unsigned)Mc[(32 + q) * TT]) << 16);
            float m3 = __uint_as_float(((unsigned)Mc[(48 + q) * TT]) << 16);
            acc0 = fmaf(rdlane(a, q),      m0, acc0);
            acc1 = fmaf(rdlane(a, 16 + q), m1, acc1);
            acc2 = fmaf(rdlane(a, 32 + q), m2, acc2);
            acc3 = fmaf(rdlane(a, 48 + q), m3, acc3);
        }
        float acc = (acc0 + acc1) + (acc2 + acc3);
        float mxv = acc;
        #pragma unroll
        for (int sh = 1; sh < 64; sh <<= 1) mxv = fmaxf(mxv, __shfl_xor(mxv, sh, 64));
        int e = (__float_as_int(mxv) >> 23) - 127;
        a = acc * __int_as_float((127 - e) << 23);
        eoff += e + eoffs[b * CH + c];
    }
    float v = a * exp2f(end_t[j] * LOG2E);
    #pragma unroll
    for (int sh = 1; sh < 64; sh <<= 1) v += __shfl_xor(v, sh, 64);
    if (j == 0) res[b] = (log2f(v) + (float)eoff) * LN2 - sc;
}

// ---------------- final mean ----------------
__global__ __launch_bounds__(64) void crf_reduce_kernel(
    const float* __restrict__ res, float* __restrict__ out)
{
    int l = threadIdx.x;
    float v = res[l] + res[l + 64];
    #pragma unroll
    for (int s = 1; s < 64; s <<= 1) v += __shfl_xor(v, s, 64);
    if (l == 0) out[0] = v * (1.0f / (float)BB);
}

extern "C" void kernel_launch(void* const* d_in, const int* in_sizes, int n_in,
                              void* d_out, int out_size, void* d_ws, size_t ws_size,
                              hipStream_t stream) {
    const float* emissions   = (const float*)d_in[0];
    const float* transitions = (const float*)d_in[1];
    const float* start_t     = (const float*)d_in[2];
    const float* end_t       = (const float*)d_in[3];
    const int*   tags        = (const int*)d_in[4];

    float* res   = (float*)d_ws;                               // 128 floats
    int*   eoffs = (int*)((char*)d_ws + 512);                  // <= 4096 ints
    unsigned short* atab = (unsigned short*)((char*)d_ws + 32768);  // 16 KB
    unsigned short* M = (unsigned short*)((char*)d_ws + 65536);

    crf_atab_kernel<<<1, 64, 0, stream>>>(transitions, atab);

    const size_t need32 = 65536 + (size_t)BB * 32 * TT * TT * 2;  // ~33.6 MB
    const size_t need16 = 65536 + (size_t)BB * 16 * TT * TT * 2;  // ~16.8 MB
    if (ws_size >= need32) {
        crf_chunk_kernel<32><<<BB * 8, 256, 0, stream>>>(emissions, atab, M, eoffs);
        crf_combine_kernel<32><<<BB, 64, 0, stream>>>(emissions, transitions, start_t,
                                                      end_t, tags, M, eoffs, res);
    } else if (ws_size >= need16) {
        crf_chunk_kernel<16><<<BB * 4, 256, 0, stream>>>(emissions, atab, M, eoffs);
        crf_combine_kernel<16><<<BB, 64, 0, stream>>>(emissions, transitions, start_t,
                                                      end_t, tags, M, eoffs, res);
    } else {
        crf_chunk_kernel<8><<<BB * 2, 256, 0, stream>>>(emissions, atab, M, eoffs);
        crf_combine_kernel<8><<<BB, 64, 0, stream>>>(emissions, transitions, start_t,
                                                     end_t, tags, M, eoffs, res);
    }
    crf_reduce_kernel<<<1, 64, 0, stream>>>(res, (float*)d_out);
}

// Round 7
// 63.256 us; speedup vs baseline: 1.8416x; 1.4370x over previous
//
#include <hip/hip_runtime.h>

// CRF loss: mean_b( log Z_b - score_b ),  B=128, S=512, T=64 (mask all-ones).
//
// Parallel associative scan: alpha_511 = alpha_0 * PROD_i (E * diag(eem_i)).
// Phase 0: A-fragment table (16 KB).
// Phase 1 (crf_chunk_kernel<CH>): per (batch, chunk) wave computes the 64x64
//   transfer matrix via the verified MFMA recurrence on identity basis.
//   NEW vs R5: eem computed once per state (1 raw v_exp per lane per step) and
//   distributed via 16 ds_bpermute (DS pipe); CUR double-buffered one step
//   ahead; em ring is 1 dword/lane/step (4 VGPR, was 64); rescale applied as
//   exact-pow2 16-mul fixup on the prebuilt CUR.
// Phase 2 (crf_combine_kernel<CH>): one wave per batch; all 64 rows of the
//   next chunk matrix preloaded into registers (double-buffered) while the
//   current matvec chains -> latency hidden. Score fused.

#define BB 128
#define SS 512
#define TT 64

typedef float f32x4 __attribute__((ext_vector_type(4)));
typedef short s16x8 __attribute__((ext_vector_type(8)));
typedef unsigned int u32x4 __attribute__((ext_vector_type(4)));

#define MFMA16(a, b, c) __builtin_amdgcn_mfma_f32_16x16x32_bf16((a), (b), (c), 0, 0, 0)

#define LOG2E 1.4426950408889634f
#define LN2   0.6931471805599453f

__device__ __forceinline__ unsigned pack_bf16_trunc(float hi, float lo) {
    return __builtin_amdgcn_perm(__float_as_uint(hi), __float_as_uint(lo), 0x07060302u);
}
__device__ __forceinline__ unsigned short bf16_rne(float x) {
    unsigned u = __float_as_uint(x);
    u += 0x7FFFu + ((u >> 16) & 1u);
    return (unsigned short)(u >> 16);
}
__device__ __forceinline__ float rdlane(float v, int lane) {
    return __uint_as_float(__builtin_amdgcn_readlane(__float_as_uint(v), lane));
}
__device__ __forceinline__ float BP(int adr, int src) {
    return __uint_as_float((unsigned)__builtin_amdgcn_ds_bpermute(adr, src));
}

// ---------------- Phase 0: A-fragment table ----------------
__global__ __launch_bounds__(64) void crf_atab_kernel(
    const float* __restrict__ transitions, unsigned short* __restrict__ atab)
{
    const int l = threadIdx.x;
    const int g = l >> 4;
    const int m = l & 15;
    #pragma unroll
    for (int t = 0; t < 4; ++t) {
        const int ps = 8 * (m >> 2) + 4 * (t & 1) + (m & 3) + 32 * (t >> 1);
        #pragma unroll
        for (int h = 0; h < 2; ++h) {
            #pragma unroll
            for (int j = 0; j < 8; ++j) {
                int k = 32 * h + 8 * g + j;
                atab[((t * 2 + h) * 64 + l) * 8 + j] =
                    bf16_rne(exp2f(transitions[k * TT + ps] * LOG2E));
            }
        }
    }
}

// ---------------- Phase 1 ----------------
template<int L>
__device__ __forceinline__ void chunk_body(
    const float* __restrict__ emb, const int sbase, const s16x8 A[4][2],
    unsigned short* __restrict__ Mout, int* __restrict__ eoff_out,
    const int g, const int m, const int l)
{
    constexpr int NG = (L - 7) / 8;      // full 8-step groups
    constexpr int TL = L - 8 * NG;       // tail steps (7 or 8)
    static_assert(TL == 7 || TL == 8, "tail");
    const f32x4 Z = {0.f, 0.f, 0.f, 0.f};
    union BU { s16x8 v; unsigned u[4]; };
    BU Blo[4], Bhi[4];
    #pragma unroll
    for (int nb = 0; nb < 4; ++nb) {
        const int K = 16 * nb + m;
        #pragma unroll
        for (int r = 0; r < 4; ++r) {
            int k0 = 8 * g + 2 * r;
            Blo[nb].u[r] = ((k0 == K) ? 0x3F80u : 0u) | ((k0 + 1 == K) ? 0x3F800000u : 0u);
            int k1 = 32 + 8 * g + 2 * r;
            Bhi[nb].u[r] = ((k1 == K) ? 0x3F80u : 0u) | ((k1 + 1 == K) ? 0x3F800000u : 0u);
        }
    }

    // bpermute byte addresses for the 16 CUR gathers (state*4), loop-invariant
    int adr[4][4];
    #pragma unroll
    for (int t = 0; t < 4; ++t)
        #pragma unroll
        for (int r = 0; r < 4; ++r)
            adr[t][r] = (8 * g + 4 * (t & 1) + r + 32 * (t >> 1)) << 2;

    // per-lane em ring: re[slot] = em[step][l]  (1 dword/lane/step)
    const float* embl = emb + l;
    float re[4];
    #pragma unroll
    for (int i = 0; i < 4; ++i) re[i] = embl[(size_t)(sbase + i) * TT];

    f32x4 CA0, CA1, CA2, CA3, CB0, CB1, CB2, CB3;
    f32x4 dfin[4][4];
    float fixs = 1.0f;
    int eoff = 0;

#define BUILD(NSL, N0, N1, N2, N3) do {                                           \
    float ee_ = __builtin_amdgcn_exp2f(re[NSL] * LOG2E);                          \
    int ei_ = __float_as_int(ee_);                                                \
    N0[0] = BP(adr[0][0], ei_); N0[1] = BP(adr[0][1], ei_);                       \
    N0[2] = BP(adr[0][2], ei_); N0[3] = BP(adr[0][3], ei_);                       \
    N1[0] = BP(adr[1][0], ei_); N1[1] = BP(adr[1][1], ei_);                       \
    N1[2] = BP(adr[1][2], ei_); N1[3] = BP(adr[1][3], ei_);                       \
    N2[0] = BP(adr[2][0], ei_); N2[1] = BP(adr[2][1], ei_);                       \
    N2[2] = BP(adr[2][2], ei_); N2[3] = BP(adr[2][3], ei_);                       \
    N3[0] = BP(adr[3][0], ei_); N3[1] = BP(adr[3][1], ei_);                       \
    N3[2] = BP(adr[3][2], ei_); N3[3] = BP(adr[3][3], ei_);                       \
} while (0)

#define NBODY(NB, RESC, U0, U1, U2, U3) do {                                      \
    f32x4 c0 = MFMA16(A[0][0], Blo[NB].v, Z);                                     \
    f32x4 c1 = MFMA16(A[1][0], Blo[NB].v, Z);                                     \
    f32x4 c2 = MFMA16(A[2][0], Blo[NB].v, Z);                                     \
    f32x4 c3 = MFMA16(A[3][0], Blo[NB].v, Z);                                     \
    c0 = MFMA16(A[0][1], Bhi[NB].v, c0);                                          \
    c1 = MFMA16(A[1][1], Bhi[NB].v, c1);                                          \
    c2 = MFMA16(A[2][1], Bhi[NB].v, c2);                                          \
    c3 = MFMA16(A[3][1], Bhi[NB].v, c3);                                          \
    c0 *= U0; c1 *= U1; c2 *= U2; c3 *= U3;                                       \
    if (RESC) {                                                                   \
        mx = fmaxf(mx, fmaxf(fmaxf(fmaxf(c0[0], c0[1]), fmaxf(c0[2], c0[3])),     \
                             fmaxf(fmaxf(c1[0], c1[1]), fmaxf(c1[2], c1[3]))));   \
        mx = fmaxf(mx, fmaxf(fmaxf(fmaxf(c2[0], c2[1]), fmaxf(c2[2], c2[3])),     \
                             fmaxf(fmaxf(c3[0], c3[1]), fmaxf(c3[2], c3[3]))));   \
    }                                                                             \
    Blo[NB].u[0] = pack_bf16_trunc(c0[1], c0[0]);                                 \
    Blo[NB].u[1] = pack_bf16_trunc(c0[3], c0[2]);                                 \
    Blo[NB].u[2] = pack_bf16_trunc(c1[1], c1[0]);                                 \
    Blo[NB].u[3] = pack_bf16_trunc(c1[3], c1[2]);                                 \
    Bhi[NB].u[0] = pack_bf16_trunc(c2[1], c2[0]);                                 \
    Bhi[NB].u[1] = pack_bf16_trunc(c2[3], c2[2]);                                 \
    Bhi[NB].u[2] = pack_bf16_trunc(c3[1], c3[0]);                                 \
    Bhi[NB].u[3] = pack_bf16_trunc(c3[3], c3[2]);                                 \
} while (0)

#define STEP(SL, NSL, U0, U1, U2, U3, N0, N1, N2, N3, FIXF, RESCF, PREF, SIDX) do { \
    BUILD(NSL, N0, N1, N2, N3);                                                   \
    if (PREF) re[SL] = embl[(size_t)(SIDX) * TT];                                 \
    if (FIXF) { U0 *= fixs; U1 *= fixs; U2 *= fixs; U3 *= fixs; }                 \
    float mx = 0.f;                                                               \
    NBODY(0, RESCF, U0, U1, U2, U3);                                              \
    NBODY(1, RESCF, U0, U1, U2, U3);                                              \
    NBODY(2, RESCF, U0, U1, U2, U3);                                              \
    NBODY(3, RESCF, U0, U1, U2, U3);                                              \
    if (RESCF) {                                                                  \
        mx = fmaxf(mx, __shfl_xor(mx, 1, 64));                                    \
        mx = fmaxf(mx, __shfl_xor(mx, 2, 64));                                    \
        mx = fmaxf(mx, __shfl_xor(mx, 4, 64));                                    \
        mx = fmaxf(mx, __shfl_xor(mx, 8, 64));                                    \
        mx = fmaxf(mx, __shfl_xor(mx, 16, 64));                                   \
        mx = fmaxf(mx, __shfl_xor(mx, 32, 64));                                   \
        int e_ = (__float_as_int(mx) >> 23) - 127;                                \
        eoff += e_;                                                               \
        fixs = __int_as_float((127 - e_) << 23);                                  \
    }                                                                             \
} while (0)

#define FINALC(U0, U1, U2, U3) do {                                               \
    _Pragma("unroll")                                                             \
    for (int nb = 0; nb < 4; ++nb) {                                              \
        f32x4 c0 = MFMA16(A[0][0], Blo[nb].v, Z);                                 \
        f32x4 c1 = MFMA16(A[1][0], Blo[nb].v, Z);                                 \
        f32x4 c2 = MFMA16(A[2][0], Blo[nb].v, Z);                                 \
        f32x4 c3 = MFMA16(A[3][0], Blo[nb].v, Z);                                 \
        c0 = MFMA16(A[0][1], Bhi[nb].v, c0);                                      \
        c1 = MFMA16(A[1][1], Bhi[nb].v, c1);                                      \
        c2 = MFMA16(A[2][1], Bhi[nb].v, c2);                                      \
        c3 = MFMA16(A[3][1], Bhi[nb].v, c3);                                      \
        dfin[nb][0] = c0 * U0;                                                    \
        dfin[nb][1] = c1 * U1;                                                    \
        dfin[nb][2] = c2 * U2;                                                    \
        dfin[nb][3] = c3 * U3;                                                    \
    }                                                                             \
} while (0)

    // CUR for step 0 from re[0]
    BUILD(0, CA0, CA1, CA2, CA3);

    #pragma unroll 1
    for (int gi = 0; gi < NG; ++gi) {
        const int s4 = sbase + 8 * gi + 4;
        STEP(0, 1, CA0, CA1, CA2, CA3, CB0, CB1, CB2, CB3, 1, 0, 1, s4 + 0);
        STEP(1, 2, CB0, CB1, CB2, CB3, CA0, CA1, CA2, CA3, 0, 0, 1, s4 + 1);
        STEP(2, 3, CA0, CA1, CA2, CA3, CB0, CB1, CB2, CB3, 0, 0, 1, s4 + 2);
        STEP(3, 0, CB0, CB1, CB2, CB3, CA0, CA1, CA2, CA3, 0, 0, 1, s4 + 3);
        STEP(0, 1, CA0, CA1, CA2, CA3, CB0, CB1, CB2, CB3, 0, 0, 1, s4 + 4);
        STEP(1, 2, CB0, CB1, CB2, CB3, CA0, CA1, CA2, CA3, 0, 0, 1, s4 + 5);
        STEP(2, 3, CA0, CA1, CA2, CA3, CB0, CB1, CB2, CB3, 0, 0, 1, s4 + 6);
        STEP(3, 0, CB0, CB1, CB2, CB3, CA0, CA1, CA2, CA3, 0, 1, 1, s4 + 7);
    }
    {
        const int t4 = sbase + 8 * NG + 4;
        if constexpr (TL == 8) {
            STEP(0, 1, CA0, CA1, CA2, CA3, CB0, CB1, CB2, CB3, 1, 0, 1, t4 + 0);
            STEP(1, 2, CB0, CB1, CB2, CB3, CA0, CA1, CA2, CA3, 0, 0, 1, t4 + 1);
            STEP(2, 3, CA0, CA1, CA2, CA3, CB0, CB1, CB2, CB3, 0, 0, 1, t4 + 2);
            STEP(3, 0, CB0, CB1, CB2, CB3, CA0, CA1, CA2, CA3, 0, 0, 1, t4 + 3);
            STEP(0, 1, CA0, CA1, CA2, CA3, CB0, CB1, CB2, CB3, 0, 0, 0, 0);
            STEP(1, 2, CB0, CB1, CB2, CB3, CA0, CA1, CA2, CA3, 0, 0, 0, 0);
            STEP(2, 3, CA0, CA1, CA2, CA3, CB0, CB1, CB2, CB3, 0, 0, 0, 0);
            FINALC(CB0, CB1, CB2, CB3);
        } else {  // TL == 7
            STEP(0, 1, CA0, CA1, CA2, CA3, CB0, CB1, CB2, CB3, 1, 0, 1, t4 + 0);
            STEP(1, 2, CB0, CB1, CB2, CB3, CA0, CA1, CA2, CA3, 0, 0, 1, t4 + 1);
            STEP(2, 3, CA0, CA1, CA2, CA3, CB0, CB1, CB2, CB3, 0, 0, 1, t4 + 2);
            STEP(3, 0, CB0, CB1, CB2, CB3, CA0, CA1, CA2, CA3, 0, 0, 0, 0);
            STEP(0, 1, CA0, CA1, CA2, CA3, CB0, CB1, CB2, CB3, 0, 0, 0, 0);
            STEP(1, 2, CB0, CB1, CB2, CB3, CA0, CA1, CA2, CA3, 0, 0, 0, 0);
            FINALC(CA0, CA1, CA2, CA3);
        }
    }
#undef FINALC
#undef STEP
#undef NBODY
#undef BUILD

    // epilogue: exact-pow2 normalize, store M[k][j] bf16
    float mx = 0.f;
    #pragma unroll
    for (int nb = 0; nb < 4; ++nb)
        #pragma unroll
        for (int t = 0; t < 4; ++t) {
            f32x4 v = dfin[nb][t];
            mx = fmaxf(mx, fmaxf(fmaxf(v[0], v[1]), fmaxf(v[2], v[3])));
        }
    #pragma unroll
    for (int sh = 1; sh < 64; sh <<= 1) mx = fmaxf(mx, __shfl_xor(mx, sh, 64));
    int e = (__float_as_int(mx) >> 23) - 127;
    eoff += e;
    const float scl = __int_as_float((127 - e) << 23);
    #pragma unroll
    for (int nb = 0; nb < 4; ++nb) {
        f32x4 d0 = dfin[nb][0] * scl, d1 = dfin[nb][1] * scl;
        f32x4 d2 = dfin[nb][2] * scl, d3 = dfin[nb][3] * scl;
        const int row = (16 * nb + m) * TT;
        u32x4 w0, w1;
        w0[0] = pack_bf16_trunc(d0[1], d0[0]);
        w0[1] = pack_bf16_trunc(d0[3], d0[2]);
        w0[2] = pack_bf16_trunc(d1[1], d1[0]);
        w0[3] = pack_bf16_trunc(d1[3], d1[2]);
        w1[0] = pack_bf16_trunc(d2[1], d2[0]);
        w1[1] = pack_bf16_trunc(d2[3], d2[2]);
        w1[2] = pack_bf16_trunc(d3[1], d3[0]);
        w1[3] = pack_bf16_trunc(d3[3], d3[2]);
        *(u32x4*)(Mout + row + 8 * g)      = w0;
        *(u32x4*)(Mout + row + 32 + 8 * g) = w1;
    }
    if (l == 0) *eoff_out = eoff;
}

template<int CH>
__global__ __launch_bounds__(256, 2) void crf_chunk_kernel(
    const float* __restrict__ emissions, const unsigned short* __restrict__ atab,
    unsigned short* __restrict__ M, int* __restrict__ eoffs)
{
    constexpr int SC = SS / CH;
    const int tid = threadIdx.x;
    const int l = tid & 63;
    const int w = tid >> 6;
    const int g = l >> 4;
    const int m = l & 15;
    const int b = blockIdx.x / (CH / 4);
    const int c = (blockIdx.x % (CH / 4)) * 4 + w;
    const float* emb = emissions + (size_t)b * SS * TT;

    s16x8 A[4][2];
    #pragma unroll
    for (int t = 0; t < 4; ++t)
        #pragma unroll
        for (int h = 0; h < 2; ++h)
            A[t][h] = *(const s16x8*)(atab + ((t * 2 + h) * 64 + l) * 8);

    unsigned short* Mout = M + (size_t)(b * CH + c) * (TT * TT);
    int* eo = eoffs + b * CH + c;
    const int sbase = SC * c + 1;
    if (c == CH - 1) chunk_body<SC - 1>(emb, sbase, A, Mout, eo, g, m, l);
    else             chunk_body<SC>(emb, sbase, A, Mout, eo, g, m, l);
}

// ---------------- Phase 2: score (fused) + chain + logsumexp ----------------
template<int CH>
__global__ __launch_bounds__(64, 1) void crf_combine_kernel(
    const float* __restrict__ emissions, const float* __restrict__ transitions,
    const float* __restrict__ start_t, const float* __restrict__ end_t,
    const int* __restrict__ tags, const unsigned short* __restrict__ M,
    const int* __restrict__ eoffs, float* __restrict__ res)
{
    const int b = blockIdx.x;
    const int j = threadIdx.x;
    const float* em = emissions + (size_t)b * SS * TT;

    // path score
    float sc = 0.f;
    #pragma unroll
    for (int r = 0; r < SS / TT; ++r) {
        int i = j + r * TT;
        int cur = tags[b * SS + i];
        if (i > 0) {
            int prev = tags[b * SS + i - 1];
            sc += transitions[prev * TT + cur] + em[i * TT + cur];
        } else {
            sc += start_t[cur] + em[cur];
        }
    }
    if (j == 0) sc += end_t[tags[b * SS + SS - 1]];
    #pragma unroll
    for (int s = 1; s < 64; s <<= 1) sc += __shfl_xor(sc, s, 64);

    // chain alpha through CH chunk matrices, double-buffered row preload
    float a = exp2f((start_t[j] + em[j]) * LOG2E);
    int eoff = 0;
    const unsigned short* Mb = M + (size_t)b * CH * (TT * TT);
    unsigned bufA[64], bufB[64];

#define LOADC(BUF, c) do {                                                        \
    const unsigned short* Mc_ = Mb + (size_t)(c) * (TT * TT) + j;                 \
    _Pragma("unroll")                                                             \
    for (int k = 0; k < 64; ++k) BUF[k] = (unsigned)Mc_[k * TT];                  \
} while (0)
#define COMPC(BUF, c) do {                                                        \
    float a0 = 0.f, a1 = 0.f, a2 = 0.f, a3 = 0.f;                                 \
    _Pragma("unroll")                                                             \
    for (int q = 0; q < 16; ++q) {                                                \
        a0 = fmaf(rdlane(a, q),      __uint_as_float(BUF[q]      << 16), a0);     \
        a1 = fmaf(rdlane(a, 16 + q), __uint_as_float(BUF[16 + q] << 16), a1);     \
        a2 = fmaf(rdlane(a, 32 + q), __uint_as_float(BUF[32 + q] << 16), a2);     \
        a3 = fmaf(rdlane(a, 48 + q), __uint_as_float(BUF[48 + q] << 16), a3);     \
    }                                                                             \
    float acc = (a0 + a1) + (a2 + a3);                                            \
    float mxv = acc;                                                              \
    _Pragma("unroll")                                                             \
    for (int sh = 1; sh < 64; sh <<= 1) mxv = fmaxf(mxv, __shfl_xor(mxv, sh, 64));\
    int e_ = (__float_as_int(mxv) >> 23) - 127;                                   \
    a = acc * __int_as_float((127 - e_) << 23);                                   \
    eoff += e_ + eoffs[b * CH + (c)];                                             \
} while (0)

    LOADC(bufA, 0);
    #pragma unroll
    for (int cp = 0; cp < CH; cp += 2) {
        LOADC(bufB, cp + 1);
        COMPC(bufA, cp);
        if (cp + 2 < CH) LOADC(bufA, cp + 2);
        COMPC(bufB, cp + 1);
    }
#undef COMPC
#undef LOADC

    float v = a * exp2f(end_t[j] * LOG2E);
    #pragma unroll
    for (int sh = 1; sh < 64; sh <<= 1) v += __shfl_xor(v, sh, 64);
    if (j == 0) res[b] = (log2f(v) + (float)eoff) * LN2 - sc;
}

// ---------------- final mean ----------------
__global__ __launch_bounds__(64) void crf_reduce_kernel(
    const float* __restrict__ res, float* __restrict__ out)
{
    int l = threadIdx.x;
    float v = res[l] + res[l + 64];
    #pragma unroll
    for (int s = 1; s < 64; s <<= 1) v += __shfl_xor(v, s, 64);
    if (l == 0) out[0] = v * (1.0f / (float)BB);
}

extern "C" void kernel_launch(void* const* d_in, const int* in_sizes, int n_in,
                              void* d_out, int out_size, void* d_ws, size_t ws_size,
                              hipStream_t stream) {
    const float* emissions   = (const float*)d_in[0];
    const float* transitions = (const float*)d_in[1];
    const float* start_t     = (const float*)d_in[2];
    const float* end_t       = (const float*)d_in[3];
    const int*   tags        = (const int*)d_in[4];

    float* res   = (float*)d_ws;                               // 128 floats
    int*   eoffs = (int*)((char*)d_ws + 512);                  // <= 2048 ints
    unsigned short* atab = (unsigned short*)((char*)d_ws + 32768);  // 16 KB
    unsigned short* M = (unsigned short*)((char*)d_ws + 65536);

    crf_atab_kernel<<<1, 64, 0, stream>>>(transitions, atab);

    const size_t need16 = 65536 + (size_t)BB * 16 * TT * TT * 2;  // ~16.8 MB
    if (ws_size >= need16) {
        crf_chunk_kernel<16><<<BB * 4, 256, 0, stream>>>(emissions, atab, M, eoffs);
        crf_combine_kernel<16><<<BB, 64, 0, stream>>>(emissions, transitions, start_t,
                                                      end_t, tags, M, eoffs, res);
    } else {
        crf_chunk_kernel<8><<<BB * 2, 256, 0, stream>>>(emissions, atab, M, eoffs);
        crf_combine_kernel<8><<<BB, 64, 0, stream>>>(emissions, transitions, start_t,
                                                     end_t, tags, M, eoffs, res);
    }
    crf_reduce_kernel<<<1, 64, 0, stream>>>(res, (float*)d_out);
}